// Round 2
// baseline (3905.177 us; speedup 1.0000x reference)
//
#include <hip/hip_runtime.h>
#include <math.h>

// ws layout (uint32 words):
//   [0      .. 4096)   hist12  (top-12-bit histogram)
//   [4096   .. 5120)   hist10a (10-bit sub-bin hist within selected b12)
//   [5120   .. 6144)   hist10b (low-10-bit exact hist within selected 22-bit prefix)
//   [6144   .. 6152)   ctrl: [0]=b12 (0xFFFFFFFF=none) [1]=kprime
//                            [2]=thr_bits [3]=cand_count [4]=prefix22 [5]=kpp
//   [6400   .. +CAP)   candidate x values (float) of selected b12
#define H12_OFF   0u
#define H10A_OFF  4096u
#define H10B_OFF  5120u
#define CTRL_OFF  6144u
#define CAND_OFF  6400u
#define CAND_CAP  921600u      // 3.6 MB; selected bin ~460K for this data
#define ZERO_WORDS 6400u       // only hists+ctrl need zeroing

// --- softplus: exact path (UNCHANGED from passing round-1 version) -------
// mimics jax.nn.softplus = max(x,0) + log1p(exp(-|x|)), each f32 step
// produced correctly-rounded via double-precision evaluation.
__device__ __forceinline__ float softplus_exact(float x) {
    float ax = fabsf(x);
    float e = (float)exp(-(double)ax);
    float l = (float)log1p((double)e);
    return fmaxf(x, 0.0f) + l;
}

// cheap: v_exp_f32-based; error <= ~(4 + ax) ulps of the result
__device__ __forceinline__ float softplus_cheap(float x) {
    float ax = fabsf(x);
    float e = __expf(-ax);
    float l = log1pf(e);
    return fmaxf(x, 0.0f) + l;
}

// conservative error margin in ulps (>=4x the analytic bound)
__device__ __forceinline__ unsigned marg_ulps(float ax) {
    return 24u + 4u * (unsigned)ax;
}

// --- K1: 12-bit histogram, cheap + margin-gated exact ---------------------
__global__ __launch_bounds__(256) void k1_hist12(
    const float* __restrict__ lg, const float* __restrict__ tg,
    unsigned* __restrict__ ws, long long n) {
    __shared__ unsigned sh[4096];
    for (int i = threadIdx.x; i < 4096; i += 256) sh[i] = 0;
    __syncthreads();

    long long n4 = n >> 2;
    long long tid = (long long)blockIdx.x * 256 + threadIdx.x;
    long long stride = (long long)gridDim.x * 256;
    const float4* lg4 = (const float4*)lg;
    const float4* tg4 = (const float4*)tg;

    for (long long i = tid; i < n4; i += stride) {
        float4 x4 = lg4[i];
        float4 t4 = tg4[i];
        float xs[4] = {x4.x, x4.y, x4.z, x4.w};
        float ts[4] = {t4.x, t4.y, t4.z, t4.w};
#pragma unroll
        for (int c = 0; c < 4; ++c) {
            if (isnan(ts[c])) {
                float x = xs[c];
                float ax = fabsf(x);
                unsigned cb = __float_as_uint(softplus_cheap(x));
                unsigned m = marg_ulps(ax);
                unsigned low = cb & 0xFFFFFu;
                if (low < m || low >= 0x100000u - m)
                    cb = __float_as_uint(softplus_exact(x));
                if (cb != 0u)              // count_nonzero semantics
                    atomicAdd(&sh[cb >> 20], 1u);
            }
        }
    }
    if (tid == 0) {
        for (long long i = (n4 << 2); i < n; ++i) {
            if (isnan(tg[i])) {
                unsigned b = __float_as_uint(softplus_exact(lg[i]));
                if (b != 0u) atomicAdd(&sh[b >> 20], 1u);
            }
        }
    }
    __syncthreads();
    unsigned* hist12 = ws + H12_OFF;
    for (int i = threadIdx.x; i < 4096; i += 256)
        if (sh[i]) atomicAdd(&hist12[i], sh[i]);
}

// --- K2: select the 12-bit bin containing the k-th largest ---------------
__global__ __launch_bounds__(256) void k2_sel12(
    unsigned* __restrict__ ws, const int* __restrict__ epoch_ptr) {
    const unsigned* hist12 = ws + H12_OFF;
    unsigned* ctrl = ws + CTRL_OFF;
    __shared__ unsigned long long chunk[256];
    int t = threadIdx.x;
    unsigned long long s = 0;
    for (int j = 0; j < 16; ++j) s += hist12[t * 16 + j];
    chunk[t] = s;
    __syncthreads();
    if (t == 0) {
        unsigned long long tot = 0;
        for (int c = 0; c < 256; ++c) tot += chunk[c];
        int epoch = epoch_ptr[0];
        float percent = fminf((float)epoch * 0.1f, 1.0f);
        float nf = (float)tot;              // astype(float32)
        float kr = rintf(nf * percent);     // jnp.round half-to-even
        long long k = (long long)kr;        // astype(int32)
        if (k < 1) k = 1;

        long long cum = 0;
        int b = -1;
        long long kprime = 0;
        for (int c = 255; c >= 0; --c) {
            if (cum + (long long)chunk[c] >= k) {
                long long cc = cum;
                for (int j = 15; j >= 0; --j) {
                    unsigned v = hist12[c * 16 + j];
                    if (cc + (long long)v >= k) {
                        b = c * 16 + j;
                        kprime = k - cc;
                        break;
                    }
                    cc += v;
                }
                break;
            }
            cum += chunk[c];
        }
        ctrl[0] = (unsigned)b;
        ctrl[1] = (unsigned)kprime;
        if (b < 0) {
            ctrl[2] = 0u;                   // threshold = 0.0f
            ctrl[4] = 0xFFFFFFFFu;
        }
    }
}

// --- K3: refine selected bin at 10-bit granularity + compact candidates --
__global__ __launch_bounds__(256) void k3_refine(
    const float* __restrict__ lg, const float* __restrict__ tg,
    unsigned* __restrict__ ws, long long n) {
    unsigned b12 = ws[CTRL_OFF + 0];
    if (b12 == 0xFFFFFFFFu) return;
    unsigned lo12 = b12 << 20;
    unsigned hi12 = lo12 + (1u << 20);

    __shared__ unsigned sh10[1024];
    for (int i = threadIdx.x; i < 1024; i += 256) sh10[i] = 0;
    __syncthreads();

    float* cand = (float*)(ws + CAND_OFF);
    unsigned* cnt = ws + CTRL_OFF + 3;

    long long n4 = n >> 2;
    long long tid = (long long)blockIdx.x * 256 + threadIdx.x;
    long long stride = (long long)gridDim.x * 256;
    const float4* lg4 = (const float4*)lg;
    const float4* tg4 = (const float4*)tg;

    for (long long i = tid; i < n4; i += stride) {
        float4 x4 = lg4[i];
        float4 t4 = tg4[i];
        float xs[4] = {x4.x, x4.y, x4.z, x4.w};
        float ts[4] = {t4.x, t4.y, t4.z, t4.w};
#pragma unroll
        for (int c = 0; c < 4; ++c) {
            if (isnan(ts[c])) {
                float x = xs[c];
                float ax = fabsf(x);
                unsigned cb = __float_as_uint(softplus_cheap(x));
                unsigned m = marg_ulps(ax);
                // gate: possible member of [lo12, hi12) within error margin
                if (cb + m >= lo12 && cb < hi12 + m) {
                    unsigned bits = cb;
                    unsigned l10 = cb & 1023u;
                    if (l10 < m || l10 >= 1024u - m)
                        bits = __float_as_uint(softplus_exact(x));
                    if (bits >= lo12 && bits < hi12) {
                        unsigned idx = atomicAdd(cnt, 1u);
                        if (idx < CAND_CAP) cand[idx] = x;
                        atomicAdd(&sh10[(bits >> 10) & 1023u], 1u);
                    }
                }
            }
        }
    }
    if (tid == 0) {
        for (long long i = (n4 << 2); i < n; ++i) {
            if (isnan(tg[i])) {
                unsigned bits = __float_as_uint(softplus_exact(lg[i]));
                if (bits >= lo12 && bits < hi12) {
                    unsigned idx = atomicAdd(cnt, 1u);
                    if (idx < CAND_CAP) cand[idx] = lg[i];
                    atomicAdd(&sh10[(bits >> 10) & 1023u], 1u);
                }
            }
        }
    }
    __syncthreads();
    for (int i = threadIdx.x; i < 1024; i += 256)
        if (sh10[i]) atomicAdd(&ws[H10A_OFF + i], sh10[i]);
}

// --- K4: select 10-bit sub-bin -------------------------------------------
__global__ __launch_bounds__(1024) void k4_sel10(unsigned* __restrict__ ws) {
    unsigned* ctrl = ws + CTRL_OFF;
    __shared__ unsigned h[1024];
    int t = threadIdx.x;
    unsigned b12 = ctrl[0];
    if (b12 == 0xFFFFFFFFu) return;
    h[t] = ws[H10A_OFF + t];
    __syncthreads();
    if (t == 0) {
        long long kprime = (long long)ctrl[1];
        long long cum = 0;
        int s = 0;
        long long kpp = 1;
        for (int j = 1023; j >= 0; --j) {
            if (cum + (long long)h[j] >= kprime) {
                s = j;
                kpp = kprime - cum;
                break;
            }
            cum += h[j];
        }
        ctrl[4] = (b12 << 10) | (unsigned)s;   // prefix22
        ctrl[5] = (unsigned)kpp;
    }
}

// --- K5: exact low-10-bit histogram within selected 22-bit prefix --------
__global__ __launch_bounds__(256) void k5_histlow(
    const float* __restrict__ lg, const float* __restrict__ tg,
    unsigned* __restrict__ ws, long long n) {
    unsigned prefix22 = ws[CTRL_OFF + 4];
    if (prefix22 == 0xFFFFFFFFu) return;
    unsigned lo = prefix22 << 10;
    unsigned hi = lo + 1024u;
    unsigned count = ws[CTRL_OFF + 3];
    const float* cand = (const float*)(ws + CAND_OFF);

    long long tid = (long long)blockIdx.x * 256 + threadIdx.x;
    long long stride = (long long)gridDim.x * 256;

    if (count <= CAND_CAP) {
        for (long long i = tid; i < (long long)count; i += stride) {
            float x = cand[i];
            float ax = fabsf(x);
            unsigned cb = __float_as_uint(softplus_cheap(x));
            unsigned m = marg_ulps(ax);
            if (cb + m >= lo && cb < hi + m) {
                unsigned b = __float_as_uint(softplus_exact(x));
                if (b >= lo && b < hi)
                    atomicAdd(&ws[H10B_OFF + (b & 1023u)], 1u);
            }
        }
    } else {
        // overflow fallback: rescan full input (never expected)
        for (long long i = tid; i < n; i += stride) {
            if (isnan(tg[i])) {
                float x = lg[i];
                float ax = fabsf(x);
                unsigned cb = __float_as_uint(softplus_cheap(x));
                unsigned m = marg_ulps(ax);
                if (cb + m >= lo && cb < hi + m) {
                    unsigned b = __float_as_uint(softplus_exact(x));
                    if (b >= lo && b < hi)
                        atomicAdd(&ws[H10B_OFF + (b & 1023u)], 1u);
                }
            }
        }
    }
}

// --- K6: exact threshold bits ---------------------------------------------
__global__ __launch_bounds__(1024) void k6_sellow(unsigned* __restrict__ ws) {
    unsigned* ctrl = ws + CTRL_OFF;
    __shared__ unsigned h[1024];
    int t = threadIdx.x;
    unsigned prefix22 = ctrl[4];
    if (prefix22 == 0xFFFFFFFFu) return;
    h[t] = ws[H10B_OFF + t];
    __syncthreads();
    if (t == 0) {
        long long kpp = (long long)ctrl[5];
        long long cum = 0;
        int bsel = 0;
        for (int j = 1023; j >= 0; --j) {
            if (cum + (long long)h[j] >= kpp) {
                bsel = j;
                break;
            }
            cum += h[j];
        }
        ctrl[2] = (prefix22 << 10) | (unsigned)bsel;
    }
}

// --- K7: output pass -------------------------------------------------------
__global__ __launch_bounds__(256) void k7_out(
    const float* __restrict__ lg, const float* __restrict__ tg,
    float* __restrict__ out, const unsigned* __restrict__ ws, long long n) {
    unsigned thr_bits = ws[CTRL_OFF + 2];

    long long n4 = n >> 2;
    long long tid = (long long)blockIdx.x * 256 + threadIdx.x;
    long long stride = (long long)gridDim.x * 256;
    const float4* lg4 = (const float4*)lg;
    const float4* tg4 = (const float4*)tg;
    float4* out4 = (float4*)out;

    for (long long i = tid; i < n4; i += stride) {
        float4 x4 = lg4[i];
        float4 t4 = tg4[i];
        float xs[4] = {x4.x, x4.y, x4.z, x4.w};
        float ts[4] = {t4.x, t4.y, t4.z, t4.w};
        float os[4];
#pragma unroll
        for (int c = 0; c < 4; ++c) {
            float x = xs[c], t = ts[c];
            float ax = fabsf(x);
            float sp = softplus_cheap(x);
            if (isnan(t)) {
                unsigned cb = __float_as_uint(sp);
                unsigned m = marg_ulps(ax);
                float loss = sp;
                bool gt;
                if (cb + m >= thr_bits && cb <= thr_bits + m) {
                    loss = softplus_exact(x);
                    gt = __float_as_uint(loss) > thr_bits;
                } else {
                    gt = cb > thr_bits;       // positive-float bit order
                }
                os[c] = gt ? 0.0f : loss;
            } else {
                os[c] = sp - x * t;
            }
        }
        float4 o = {os[0], os[1], os[2], os[3]};
        out4[i] = o;
    }
    if (tid == 0) {
        for (long long i = (n4 << 2); i < n; ++i) {
            float x = lg[i], t = tg[i];
            if (isnan(t)) {
                float loss = softplus_exact(x);
                out[i] = (__float_as_uint(loss) > thr_bits) ? 0.0f : loss;
            } else {
                out[i] = softplus_exact(x) - x * t;
            }
        }
    }
}

extern "C" void kernel_launch(void* const* d_in, const int* in_sizes, int n_in,
                              void* d_out, int out_size, void* d_ws, size_t ws_size,
                              hipStream_t stream) {
    const float* lg = (const float*)d_in[0];
    const float* tg = (const float*)d_in[1];
    const int* epoch = (const int*)d_in[2];
    float* out = (float*)d_out;
    unsigned* ws = (unsigned*)d_ws;
    long long n = (long long)in_sizes[0];

    hipMemsetAsync(d_ws, 0, (size_t)ZERO_WORDS * 4, stream);

    const int blocks = 2048, threads = 256;
    k1_hist12<<<blocks, threads, 0, stream>>>(lg, tg, ws, n);
    k2_sel12<<<1, 256, 0, stream>>>(ws, epoch);
    k3_refine<<<blocks, threads, 0, stream>>>(lg, tg, ws, n);
    k4_sel10<<<1, 1024, 0, stream>>>(ws);
    k5_histlow<<<blocks, threads, 0, stream>>>(lg, tg, ws, n);
    k6_sellow<<<1, 1024, 0, stream>>>(ws);
    k7_out<<<blocks, threads, 0, stream>>>(lg, tg, out, ws, n);
}

// Round 3
// 406.688 us; speedup vs baseline: 9.6024x; 9.6024x over previous
//
#include <hip/hip_runtime.h>
#include <math.h>

// ws layout (uint32 words):
//   [0      .. 4096)   hist12  (top-12-bit histogram)
//   [4096   .. 5120)   hist10a (10-bit sub-bin hist within selected b12)
//   [5120   .. 6144)   hist10b (low-10-bit exact hist within selected 22-bit prefix)
//   [6144   .. 6152)   ctrl: [0]=b12 (0xFFFFFFFF=none) [1]=kprime
//                            [2]=thr_bits [3]=cand_count [4]=prefix22 [5]=kpp
//   [6400   .. +CAP)   candidate x values (float) of selected b12
#define H12_OFF   0u
#define H10A_OFF  4096u
#define H10B_OFF  5120u
#define CTRL_OFF  6144u
#define CAND_OFF  6400u
#define CAND_CAP  921600u      // 3.6 MB; selected bin ~460K for this data
#define ZERO_WORDS 6400u       // only hists+ctrl need zeroing
#define LBUF      4096u        // per-block LDS candidate buffer (floats)

// --- softplus: exact path (UNCHANGED from passing rounds 1-2) ------------
// mimics jax.nn.softplus = max(x,0) + log1p(exp(-|x|)), each f32 step
// produced correctly-rounded via double-precision evaluation.
__device__ __forceinline__ float softplus_exact(float x) {
    float ax = fabsf(x);
    float e = (float)exp(-(double)ax);
    float l = (float)log1p((double)e);
    return fmaxf(x, 0.0f) + l;
}

// cheap: v_exp_f32-based; error <= ~(4 + ax) ulps of the result
__device__ __forceinline__ float softplus_cheap(float x) {
    float ax = fabsf(x);
    float e = __expf(-ax);
    float l = log1pf(e);
    return fmaxf(x, 0.0f) + l;
}

// conservative error margin in ulps (>=4x the analytic bound)
__device__ __forceinline__ unsigned marg_ulps(float ax) {
    return 24u + 4u * (unsigned)ax;
}

// --- K1: 12-bit histogram, cheap + margin-gated exact ---------------------
__global__ __launch_bounds__(256) void k1_hist12(
    const float* __restrict__ lg, const float* __restrict__ tg,
    unsigned* __restrict__ ws, long long n) {
    __shared__ unsigned sh[4096];
    for (int i = threadIdx.x; i < 4096; i += 256) sh[i] = 0;
    __syncthreads();

    long long n4 = n >> 2;
    long long tid = (long long)blockIdx.x * 256 + threadIdx.x;
    long long stride = (long long)gridDim.x * 256;
    const float4* lg4 = (const float4*)lg;
    const float4* tg4 = (const float4*)tg;

    for (long long i = tid; i < n4; i += stride) {
        float4 x4 = lg4[i];
        float4 t4 = tg4[i];
        float xs[4] = {x4.x, x4.y, x4.z, x4.w};
        float ts[4] = {t4.x, t4.y, t4.z, t4.w};
#pragma unroll
        for (int c = 0; c < 4; ++c) {
            if (isnan(ts[c])) {
                float x = xs[c];
                float ax = fabsf(x);
                unsigned cb = __float_as_uint(softplus_cheap(x));
                unsigned m = marg_ulps(ax);
                unsigned low = cb & 0xFFFFFu;
                if (low < m || low >= 0x100000u - m)
                    cb = __float_as_uint(softplus_exact(x));
                if (cb != 0u)              // count_nonzero semantics
                    atomicAdd(&sh[cb >> 20], 1u);
            }
        }
    }
    if (tid == 0) {
        for (long long i = (n4 << 2); i < n; ++i) {
            if (isnan(tg[i])) {
                unsigned b = __float_as_uint(softplus_exact(lg[i]));
                if (b != 0u) atomicAdd(&sh[b >> 20], 1u);
            }
        }
    }
    __syncthreads();
    unsigned* hist12 = ws + H12_OFF;
    for (int i = threadIdx.x; i < 4096; i += 256)
        if (sh[i]) atomicAdd(&hist12[i], sh[i]);
}

// --- K2: select the 12-bit bin containing the k-th largest ---------------
__global__ __launch_bounds__(256) void k2_sel12(
    unsigned* __restrict__ ws, const int* __restrict__ epoch_ptr) {
    const unsigned* hist12 = ws + H12_OFF;
    unsigned* ctrl = ws + CTRL_OFF;
    __shared__ unsigned long long chunk[256];
    int t = threadIdx.x;
    unsigned long long s = 0;
    for (int j = 0; j < 16; ++j) s += hist12[t * 16 + j];
    chunk[t] = s;
    __syncthreads();
    if (t == 0) {
        unsigned long long tot = 0;
        for (int c = 0; c < 256; ++c) tot += chunk[c];
        int epoch = epoch_ptr[0];
        float percent = fminf((float)epoch * 0.1f, 1.0f);
        float nf = (float)tot;              // astype(float32)
        float kr = rintf(nf * percent);     // jnp.round half-to-even
        long long k = (long long)kr;        // astype(int32)
        if (k < 1) k = 1;

        long long cum = 0;
        int b = -1;
        long long kprime = 0;
        for (int c = 255; c >= 0; --c) {
            if (cum + (long long)chunk[c] >= k) {
                long long cc = cum;
                for (int j = 15; j >= 0; --j) {
                    unsigned v = hist12[c * 16 + j];
                    if (cc + (long long)v >= k) {
                        b = c * 16 + j;
                        kprime = k - cc;
                        break;
                    }
                    cc += v;
                }
                break;
            }
            cum += chunk[c];
        }
        ctrl[0] = (unsigned)b;
        ctrl[1] = (unsigned)kprime;
        if (b < 0) {
            ctrl[2] = 0u;                   // threshold = 0.0f
            ctrl[4] = 0xFFFFFFFFu;
        }
    }
}

// --- K3: refine selected bin at 10-bit granularity + compact candidates --
// Compaction is per-block LDS-buffered: one global atomicAdd per block.
__global__ __launch_bounds__(256) void k3_refine(
    const float* __restrict__ lg, const float* __restrict__ tg,
    unsigned* __restrict__ ws, long long n) {
    unsigned b12 = ws[CTRL_OFF + 0];
    if (b12 == 0xFFFFFFFFu) return;
    unsigned lo12 = b12 << 20;
    unsigned hi12 = lo12 + (1u << 20);

    __shared__ unsigned sh10[1024];
    __shared__ float buf[LBUF];
    __shared__ unsigned lcnt;
    __shared__ unsigned gbase;
    for (int i = threadIdx.x; i < 1024; i += 256) sh10[i] = 0;
    if (threadIdx.x == 0) lcnt = 0;
    __syncthreads();

    float* cand = (float*)(ws + CAND_OFF);
    unsigned* cnt = ws + CTRL_OFF + 3;

    long long n4 = n >> 2;
    long long tid = (long long)blockIdx.x * 256 + threadIdx.x;
    long long stride = (long long)gridDim.x * 256;
    const float4* lg4 = (const float4*)lg;
    const float4* tg4 = (const float4*)tg;

    for (long long i = tid; i < n4; i += stride) {
        float4 x4 = lg4[i];
        float4 t4 = tg4[i];
        float xs[4] = {x4.x, x4.y, x4.z, x4.w};
        float ts[4] = {t4.x, t4.y, t4.z, t4.w};
#pragma unroll
        for (int c = 0; c < 4; ++c) {
            if (isnan(ts[c])) {
                float x = xs[c];
                float ax = fabsf(x);
                unsigned cb = __float_as_uint(softplus_cheap(x));
                unsigned m = marg_ulps(ax);
                // gate: possible member of [lo12, hi12) within error margin
                if (cb + m >= lo12 && cb < hi12 + m) {
                    unsigned bits = cb;
                    unsigned l10 = cb & 1023u;
                    if (l10 < m || l10 >= 1024u - m)
                        bits = __float_as_uint(softplus_exact(x));
                    if (bits >= lo12 && bits < hi12) {
                        unsigned li = atomicAdd(&lcnt, 1u);   // LDS atomic
                        if (li < LBUF) buf[li] = x;
                        atomicAdd(&sh10[(bits >> 10) & 1023u], 1u);
                    }
                }
            }
        }
    }
    if (tid == 0) {  // scalar tail (empty for n % 4 == 0): direct append
        for (long long i = (n4 << 2); i < n; ++i) {
            if (isnan(tg[i])) {
                unsigned bits = __float_as_uint(softplus_exact(lg[i]));
                if (bits >= lo12 && bits < hi12) {
                    unsigned idx = atomicAdd(cnt, 1u);
                    if (idx < CAND_CAP) cand[idx] = lg[i];
                    atomicAdd(&sh10[(bits >> 10) & 1023u], 1u);
                }
            }
        }
    }
    __syncthreads();
    // merge sub-bin histogram
    for (int i = threadIdx.x; i < 1024; i += 256)
        if (sh10[i]) atomicAdd(&ws[H10A_OFF + i], sh10[i]);
    // flush candidate buffer: one reservation per block
    if (threadIdx.x == 0) {
        // on LDS overflow, poison the count so K5 takes the rescan fallback
        unsigned add = (lcnt > LBUF) ? (CAND_CAP + 1u) : lcnt;
        gbase = atomicAdd(cnt, add);
    }
    __syncthreads();
    unsigned c = lcnt < LBUF ? lcnt : LBUF;
    for (unsigned i = threadIdx.x; i < c; i += 256) {
        unsigned gi = gbase + i;
        if (gi < CAND_CAP) cand[gi] = buf[i];
    }
}

// --- K4: select 10-bit sub-bin -------------------------------------------
__global__ __launch_bounds__(1024) void k4_sel10(unsigned* __restrict__ ws) {
    unsigned* ctrl = ws + CTRL_OFF;
    __shared__ unsigned h[1024];
    int t = threadIdx.x;
    unsigned b12 = ctrl[0];
    if (b12 == 0xFFFFFFFFu) return;
    h[t] = ws[H10A_OFF + t];
    __syncthreads();
    if (t == 0) {
        long long kprime = (long long)ctrl[1];
        long long cum = 0;
        int s = 0;
        long long kpp = 1;
        for (int j = 1023; j >= 0; --j) {
            if (cum + (long long)h[j] >= kprime) {
                s = j;
                kpp = kprime - cum;
                break;
            }
            cum += h[j];
        }
        ctrl[4] = (b12 << 10) | (unsigned)s;   // prefix22
        ctrl[5] = (unsigned)kpp;
    }
}

// --- K5: exact low-10-bit histogram within selected 22-bit prefix --------
__global__ __launch_bounds__(256) void k5_histlow(
    const float* __restrict__ lg, const float* __restrict__ tg,
    unsigned* __restrict__ ws, long long n) {
    unsigned prefix22 = ws[CTRL_OFF + 4];
    if (prefix22 == 0xFFFFFFFFu) return;
    unsigned lo = prefix22 << 10;
    unsigned hi = lo + 1024u;
    unsigned count = ws[CTRL_OFF + 3];
    const float* cand = (const float*)(ws + CAND_OFF);

    long long tid = (long long)blockIdx.x * 256 + threadIdx.x;
    long long stride = (long long)gridDim.x * 256;

    if (count <= CAND_CAP) {
        for (long long i = tid; i < (long long)count; i += stride) {
            float x = cand[i];
            float ax = fabsf(x);
            unsigned cb = __float_as_uint(softplus_cheap(x));
            unsigned m = marg_ulps(ax);
            if (cb + m >= lo && cb < hi + m) {
                unsigned b = __float_as_uint(softplus_exact(x));
                if (b >= lo && b < hi)
                    atomicAdd(&ws[H10B_OFF + (b & 1023u)], 1u);
            }
        }
    } else {
        // overflow fallback: rescan full input (never expected)
        for (long long i = tid; i < n; i += stride) {
            if (isnan(tg[i])) {
                float x = lg[i];
                float ax = fabsf(x);
                unsigned cb = __float_as_uint(softplus_cheap(x));
                unsigned m = marg_ulps(ax);
                if (cb + m >= lo && cb < hi + m) {
                    unsigned b = __float_as_uint(softplus_exact(x));
                    if (b >= lo && b < hi)
                        atomicAdd(&ws[H10B_OFF + (b & 1023u)], 1u);
                }
            }
        }
    }
}

// --- K6: exact threshold bits ---------------------------------------------
__global__ __launch_bounds__(1024) void k6_sellow(unsigned* __restrict__ ws) {
    unsigned* ctrl = ws + CTRL_OFF;
    __shared__ unsigned h[1024];
    int t = threadIdx.x;
    unsigned prefix22 = ctrl[4];
    if (prefix22 == 0xFFFFFFFFu) return;
    h[t] = ws[H10B_OFF + t];
    __syncthreads();
    if (t == 0) {
        long long kpp = (long long)ctrl[5];
        long long cum = 0;
        int bsel = 0;
        for (int j = 1023; j >= 0; --j) {
            if (cum + (long long)h[j] >= kpp) {
                bsel = j;
                break;
            }
            cum += h[j];
        }
        ctrl[2] = (prefix22 << 10) | (unsigned)bsel;
    }
}

// --- K7: output pass -------------------------------------------------------
__global__ __launch_bounds__(256) void k7_out(
    const float* __restrict__ lg, const float* __restrict__ tg,
    float* __restrict__ out, const unsigned* __restrict__ ws, long long n) {
    unsigned thr_bits = ws[CTRL_OFF + 2];

    long long n4 = n >> 2;
    long long tid = (long long)blockIdx.x * 256 + threadIdx.x;
    long long stride = (long long)gridDim.x * 256;
    const float4* lg4 = (const float4*)lg;
    const float4* tg4 = (const float4*)tg;
    float4* out4 = (float4*)out;

    for (long long i = tid; i < n4; i += stride) {
        float4 x4 = lg4[i];
        float4 t4 = tg4[i];
        float xs[4] = {x4.x, x4.y, x4.z, x4.w};
        float ts[4] = {t4.x, t4.y, t4.z, t4.w};
        float os[4];
#pragma unroll
        for (int c = 0; c < 4; ++c) {
            float x = xs[c], t = ts[c];
            float ax = fabsf(x);
            float sp = softplus_cheap(x);
            if (isnan(t)) {
                unsigned cb = __float_as_uint(sp);
                unsigned m = marg_ulps(ax);
                float loss = sp;
                bool gt;
                if (cb + m >= thr_bits && cb <= thr_bits + m) {
                    loss = softplus_exact(x);
                    gt = __float_as_uint(loss) > thr_bits;
                } else {
                    gt = cb > thr_bits;       // positive-float bit order
                }
                os[c] = gt ? 0.0f : loss;
            } else {
                os[c] = sp - x * t;
            }
        }
        float4 o = {os[0], os[1], os[2], os[3]};
        out4[i] = o;
    }
    if (tid == 0) {
        for (long long i = (n4 << 2); i < n; ++i) {
            float x = lg[i], t = tg[i];
            if (isnan(t)) {
                float loss = softplus_exact(x);
                out[i] = (__float_as_uint(loss) > thr_bits) ? 0.0f : loss;
            } else {
                out[i] = softplus_exact(x) - x * t;
            }
        }
    }
}

extern "C" void kernel_launch(void* const* d_in, const int* in_sizes, int n_in,
                              void* d_out, int out_size, void* d_ws, size_t ws_size,
                              hipStream_t stream) {
    const float* lg = (const float*)d_in[0];
    const float* tg = (const float*)d_in[1];
    const int* epoch = (const int*)d_in[2];
    float* out = (float*)d_out;
    unsigned* ws = (unsigned*)d_ws;
    long long n = (long long)in_sizes[0];

    hipMemsetAsync(d_ws, 0, (size_t)ZERO_WORDS * 4, stream);

    const int blocks = 2048, threads = 256;
    k1_hist12<<<blocks, threads, 0, stream>>>(lg, tg, ws, n);
    k2_sel12<<<1, 256, 0, stream>>>(ws, epoch);
    k3_refine<<<blocks, threads, 0, stream>>>(lg, tg, ws, n);
    k4_sel10<<<1, 1024, 0, stream>>>(ws);
    k5_histlow<<<blocks, threads, 0, stream>>>(lg, tg, ws, n);
    k6_sellow<<<1, 1024, 0, stream>>>(ws);
    k7_out<<<blocks, threads, 0, stream>>>(lg, tg, out, ws, n);
}

// Round 4
// 257.230 us; speedup vs baseline: 15.1816x; 1.5810x over previous
//
#include <hip/hip_runtime.h>
#include <math.h>

// ws layout (uint32 words):
//   [0     .. 16384)  histC  (exact low-bits hist over selected 2^14 window)
//   [16384 .. 20480)  hist12 (top-12-bit histogram)
//   [20480 .. 20544)  hist64 (64 sub-bins of width 2^14 within selected b12)
//   [20544 .. 20560)  ctrl: [0]=b12 (0xFFFFFFFF=none) [1]=kprime [2]=thr_bits
//                           [4]=win_lo_bits (0xFFFFFFFF=none) [5]=kpp [6]=m_bin
#define HC_OFF     0u
#define H12_OFF    16384u
#define H64_OFF    20480u
#define CTRL_OFF   20544u
#define ZERO_WORDS 20560u

#define FLOOR_BITS 0x36000000u   // bits(2^-19): below this, cheap is unreliable

// --- exact softplus (UNCHANGED from passing rounds 1-3) ------------------
// mimics jax.nn.softplus = max(x,0) + log1p(exp(-|x|)), each f32 step
// produced correctly-rounded via double-precision evaluation.
__device__ __forceinline__ float softplus_exact(float x) {
    float ax = fabsf(x);
    float e = (float)exp(-(double)ax);
    float l = (float)log1p((double)e);
    return fmaxf(x, 0.0f) + l;
}
__device__ __forceinline__ unsigned exact_bits(float x) {
    return __float_as_uint(softplus_exact(x));
}

// --- pass-A refinement: hand-rolled cheap softplus + margin-gated exact --
// cheap: sp = max(x,0) + __logf(1 + __expf(-ax))  (v_exp/v_log native)
// error bound (ulps of result): 64 + 8*ax + (x<0 ? e^{ax} : 0); floor gate
// below 2^-19. Elements within margin of a 2^20-bin edge -> exact f64.
__device__ __forceinline__ unsigned refine_A(float x, float* spo) {
    float ax = fabsf(x);
    float e = __expf(-ax);
    float sp = fmaxf(x, 0.0f) + __logf(1.0f + e);
    unsigned cb = __float_as_uint(sp);
    float mf = 64.0f + 8.0f * ax;
    if (x < 0.0f) mf += __builtin_amdgcn_rcpf(e);   // e^{ax} term
    bool need = (cb < FLOOR_BITS) || (mf >= 524288.0f);
    if (!need) {
        unsigned m = (unsigned)mf;
        unsigned low = cb & 0xFFFFFu;
        need = (low < m) || (low >= 0x100000u - m);
    }
    if (need) {
        sp = softplus_exact(x);
        cb = __float_as_uint(sp);
    }
    *spo = sp;
    return cb;
}

// --- kA: stream logits+targets; store refined bits to out; hist12 --------
// unknown: out = +loss (refined bits). known: out = -(loss) (sign tag).
__global__ __launch_bounds__(256) void kA_store_hist(
    const float* __restrict__ lg, const float* __restrict__ tg,
    float* __restrict__ out, unsigned* __restrict__ ws, long long n) {
    __shared__ unsigned sh[2][4096];
    for (int i = threadIdx.x; i < 4096; i += 256) { sh[0][i] = 0; sh[1][i] = 0; }
    __syncthreads();
    int hsel = threadIdx.x & 1;

    long long n4 = n >> 2;
    long long tid = (long long)blockIdx.x * 256 + threadIdx.x;
    long long stride = (long long)gridDim.x * 256;
    const float4* lg4 = (const float4*)lg;
    const float4* tg4 = (const float4*)tg;
    float4* out4 = (float4*)out;

    for (long long i = tid; i < n4; i += stride) {
        float4 x4 = lg4[i];
        float4 t4 = tg4[i];
        float xs[4] = {x4.x, x4.y, x4.z, x4.w};
        float ts[4] = {t4.x, t4.y, t4.z, t4.w};
        float os[4];
#pragma unroll
        for (int c = 0; c < 4; ++c) {
            float x = xs[c], t = ts[c];
            if (isnan(t)) {
                float sp;
                unsigned cb = refine_A(x, &sp);
                if (cb != 0u) atomicAdd(&sh[hsel][cb >> 20], 1u);
                os[c] = sp;                         // bits == cb
            } else {
                float ax = fabsf(x);
                float sp = fmaxf(x, 0.0f) + __logf(1.0f + __expf(-ax));
                float loss = sp - x * t;            // > 0 always
                os[c] = __uint_as_float(__float_as_uint(loss) ^ 0x80000000u);
            }
        }
        float4 o = {os[0], os[1], os[2], os[3]};
        out4[i] = o;
    }
    if (tid == 0) {   // scalar tail (n % 4 == 0 here; kept for generality)
        for (long long i = (n4 << 2); i < n; ++i) {
            float x = lg[i], t = tg[i];
            if (isnan(t)) {
                float sp;
                unsigned cb = refine_A(x, &sp);
                if (cb != 0u) atomicAdd(&sh[0][cb >> 20], 1u);
                out[i] = sp;
            } else {
                float sp = fmaxf(x, 0.0f) + __logf(1.0f + __expf(-fabsf(x)));
                float loss = sp - x * t;
                out[i] = __uint_as_float(__float_as_uint(loss) ^ 0x80000000u);
            }
        }
    }
    __syncthreads();
    unsigned* hist12 = ws + H12_OFF;
    for (int i = threadIdx.x; i < 4096; i += 256) {
        unsigned v = sh[0][i] + sh[1][i];
        if (v) atomicAdd(&hist12[i], v);
    }
}

// --- k2: select 12-bit bin; compute k, kprime, and bin-wide margin -------
__global__ __launch_bounds__(256) void k2_sel12(
    unsigned* __restrict__ ws, const int* __restrict__ epoch_ptr) {
    const unsigned* hist12 = ws + H12_OFF;
    unsigned* ctrl = ws + CTRL_OFF;
    __shared__ unsigned long long chunk[256];
    int t = threadIdx.x;
    unsigned long long s = 0;
    for (int j = 0; j < 16; ++j) s += hist12[t * 16 + j];
    chunk[t] = s;
    __syncthreads();
    if (t == 0) {
        unsigned long long tot = 0;
        for (int c = 0; c < 256; ++c) tot += chunk[c];
        int epoch = epoch_ptr[0];
        float percent = fminf((float)epoch * 0.1f, 1.0f);
        float nf = (float)tot;              // astype(float32)
        float kr = rintf(nf * percent);     // jnp.round half-to-even
        long long k = (long long)kr;        // astype(int32)
        if (k < 1) k = 1;

        long long cum = 0;
        int b = -1;
        long long kprime = 0;
        for (int c = 255; c >= 0; --c) {
            if (cum + (long long)chunk[c] >= k) {
                long long cc = cum;
                for (int j = 15; j >= 0; --j) {
                    unsigned v = hist12[c * 16 + j];
                    if (cc + (long long)v >= k) {
                        b = c * 16 + j;
                        kprime = k - cc;
                        break;
                    }
                    cc += v;
                }
                break;
            }
            cum += chunk[c];
        }
        ctrl[0] = (unsigned)b;
        ctrl[1] = (unsigned)kprime;
        if (b < 0) {
            ctrl[2] = 0u;                   // threshold = 0.0f
            ctrl[4] = 0xFFFFFFFFu;          // no window
            ctrl[6] = 0u;
        } else {
            // bin-wide margin: worst per-element cheap-error over the bin's
            // x-range (unknown loss = softplus(x) is monotone in x).
            unsigned lo12 = (unsigned)b << 20;
            double vlo = (double)__uint_as_float(lo12);
            double vhi = (double)__uint_as_float(lo12 + 0xFFFFFu);
            double mb = 1e9;
            if (vlo > 1e-30) {
                double xlo = vlo + log1p(-exp(-vlo)) - 0.001;  // inv_softplus
                double xhi = vhi + log1p(-exp(-vhi)) + 0.001;
                double axmax = fmax(fabs(xlo), fabs(xhi));
                mb = 64.0 + 8.0 * ceil(axmax);
                if (xlo < 0.0) mb += exp(fmin(-xlo, 30.0));
                mb *= 2.0;                  // safety factor
            }
            ctrl[6] = (mb >= 8192.0) ? 8192u : (unsigned)mb;
        }
    }
}

// --- kB: 64-sub-bin histogram within selected bin (bit-compares only) ----
__global__ __launch_bounds__(256) void kB_hist64(
    const float* __restrict__ lg, const unsigned* __restrict__ ob,
    unsigned* __restrict__ ws, long long n) {
    unsigned b12 = ws[CTRL_OFF + 0];
    if (b12 == 0xFFFFFFFFu) return;
    unsigned lo12 = b12 << 20;
    unsigned hi12 = lo12 + (1u << 20);
    unsigned m = ws[CTRL_OFF + 6];

    __shared__ unsigned sh[64];
    if (threadIdx.x < 64) sh[threadIdx.x] = 0;
    __syncthreads();

    long long n4 = n >> 2;
    long long tid = (long long)blockIdx.x * 256 + threadIdx.x;
    long long stride = (long long)gridDim.x * 256;
    const uint4* o4 = (const uint4*)ob;

    for (long long i = tid; i < n4; i += stride) {
        uint4 u4 = o4[i];
        unsigned us[4] = {u4.x, u4.y, u4.z, u4.w};
#pragma unroll
        for (int c = 0; c < 4; ++c) {
            unsigned u = us[c];
            // knowns have sign bit set -> u >= 2^31 >= hi12 -> excluded
            if (u != 0u && u >= lo12 && u < hi12) {
                unsigned rB = u;
                unsigned d = u & 16383u;
                if (d < m || d >= 16384u - m)
                    rB = exact_bits(lg[i * 4 + c]);   // edge: resolve exactly
                atomicAdd(&sh[(rB >> 14) & 63u], 1u);
            }
        }
    }
    if (tid == 0) {
        for (long long i = (n4 << 2); i < n; ++i) {
            unsigned u = ob[i];
            if (u != 0u && u >= lo12 && u < hi12) {
                unsigned rB = u;
                unsigned d = u & 16383u;
                if (d < m || d >= 16384u - m) rB = exact_bits(lg[i]);
                atomicAdd(&sh[(rB >> 14) & 63u], 1u);
            }
        }
    }
    __syncthreads();
    if (threadIdx.x < 64 && sh[threadIdx.x])
        atomicAdd(&ws[H64_OFF + threadIdx.x], sh[threadIdx.x]);
}

// --- k4: select 2^14-wide window ------------------------------------------
__global__ void k4_sel64(unsigned* __restrict__ ws) {
    unsigned* ctrl = ws + CTRL_OFF;
    if (ctrl[0] == 0xFFFFFFFFu) return;
    if (threadIdx.x == 0) {
        long long kprime = (long long)ctrl[1];
        long long cum = 0;
        int s = 0;
        long long kpp = 1;
        for (int j = 63; j >= 0; --j) {
            unsigned v = ws[H64_OFF + j];
            if (cum + (long long)v >= kprime) {
                s = j;
                kpp = kprime - cum;
                break;
            }
            cum += v;
        }
        ctrl[4] = (ctrl[0] << 20) + ((unsigned)s << 14);
        ctrl[5] = (unsigned)kpp;
    }
}

// --- kC: exact histogram over the selected window -------------------------
__global__ __launch_bounds__(256) void kC_histwin(
    const float* __restrict__ lg, const unsigned* __restrict__ ob,
    unsigned* __restrict__ ws, long long n) {
    unsigned wlo = ws[CTRL_OFF + 4];
    if (wlo == 0xFFFFFFFFu) return;
    unsigned whi = wlo + 16384u;
    unsigned m = ws[CTRL_OFF + 6];
    unsigned b12 = ws[CTRL_OFF + 0];
    unsigned lo12 = b12 << 20;
    unsigned hi12 = lo12 + (1u << 20);
    unsigned glo = (wlo - lo12 > m) ? wlo - m : lo12;
    unsigned ghi = (hi12 - whi > m) ? whi + m : hi12;

    long long n4 = n >> 2;
    long long tid = (long long)blockIdx.x * 256 + threadIdx.x;
    long long stride = (long long)gridDim.x * 256;
    const uint4* o4 = (const uint4*)ob;

    for (long long i = tid; i < n4; i += stride) {
        uint4 u4 = o4[i];
        unsigned us[4] = {u4.x, u4.y, u4.z, u4.w};
#pragma unroll
        for (int c = 0; c < 4; ++c) {
            unsigned u = us[c];
            if (u != 0u && u >= glo && u < ghi) {
                float x = lg[i * 4 + c];
                unsigned eb = exact_bits(x);
                unsigned rB = u;
                unsigned d = u & 16383u;
                if (d < m || d >= 16384u - m) rB = eb;  // membership by refined
                if (rB >= wlo && rB < whi) {
                    unsigned off = eb - wlo;
                    if (off < 16384u) atomicAdd(&ws[HC_OFF + off], 1u);
                }
            }
        }
    }
    if (tid == 0) {
        for (long long i = (n4 << 2); i < n; ++i) {
            unsigned u = ob[i];
            if (u != 0u && u >= glo && u < ghi) {
                unsigned eb = exact_bits(lg[i]);
                unsigned rB = u;
                unsigned d = u & 16383u;
                if (d < m || d >= 16384u - m) rB = eb;
                if (rB >= wlo && rB < whi) {
                    unsigned off = eb - wlo;
                    if (off < 16384u) atomicAdd(&ws[HC_OFF + off], 1u);
                }
            }
        }
    }
}

// --- k6: exact threshold bits from histC ----------------------------------
__global__ __launch_bounds__(1024) void k6_selwin(unsigned* __restrict__ ws) {
    unsigned* ctrl = ws + CTRL_OFF;
    if (ctrl[4] == 0xFFFFFFFFu) return;
    __shared__ unsigned long long csum[1024];
    int t = threadIdx.x;
    unsigned long long s = 0;
    for (int j = 0; j < 16; ++j) s += ws[HC_OFF + t * 16 + j];
    csum[t] = s;
    __syncthreads();
    if (t == 0) {
        long long kpp = (long long)ctrl[5];
        long long cum = 0;
        int sel = 0;
        long long rem = kpp;
        for (int c = 1023; c >= 0; --c) {
            if (cum + (long long)csum[c] >= kpp) {
                sel = c;
                rem = kpp - cum;
                break;
            }
            cum += csum[c];
        }
        long long cc = 0;
        int bsel = 0;
        for (int j = 15; j >= 0; --j) {
            unsigned v = ws[HC_OFF + sel * 16 + j];
            if (cc + (long long)v >= rem) {
                bsel = j;
                break;
            }
            cc += v;
        }
        ctrl[2] = ctrl[4] + (unsigned)(sel * 16 + bsel);
    }
}

// --- kD: final in-place rewrite of out -------------------------------------
__global__ __launch_bounds__(256) void kD_final(
    const float* __restrict__ lg, unsigned* __restrict__ ob,
    const unsigned* __restrict__ ws, long long n) {
    unsigned thr = ws[CTRL_OFF + 2];
    unsigned m = ws[CTRL_OFF + 6];

    long long n4 = n >> 2;
    long long tid = (long long)blockIdx.x * 256 + threadIdx.x;
    long long stride = (long long)gridDim.x * 256;
    uint4* o4 = (uint4*)ob;

    for (long long i = tid; i < n4; i += stride) {
        uint4 u4 = o4[i];
        unsigned us[4] = {u4.x, u4.y, u4.z, u4.w};
        unsigned vs[4];
#pragma unroll
        for (int c = 0; c < 4; ++c) {
            unsigned u = us[c];
            if (u & 0x80000000u) {
                vs[c] = u ^ 0x80000000u;            // known: restore loss
            } else {
                unsigned udiff = (u > thr) ? u - thr : thr - u;
                if (udiff <= m) {                   // banded: exact decision
                    unsigned eb = exact_bits(lg[i * 4 + c]);
                    vs[c] = (eb > thr) ? 0u : eb;
                } else {
                    vs[c] = (u > thr) ? 0u : u;
                }
            }
        }
        uint4 v4 = {vs[0], vs[1], vs[2], vs[3]};
        o4[i] = v4;
    }
    if (tid == 0) {
        for (long long i = (n4 << 2); i < n; ++i) {
            unsigned u = ob[i];
            if (u & 0x80000000u) {
                ob[i] = u ^ 0x80000000u;
            } else {
                unsigned udiff = (u > thr) ? u - thr : thr - u;
                if (udiff <= m) {
                    unsigned eb = exact_bits(lg[i]);
                    ob[i] = (eb > thr) ? 0u : eb;
                } else {
                    ob[i] = (u > thr) ? 0u : u;
                }
            }
        }
    }
}

extern "C" void kernel_launch(void* const* d_in, const int* in_sizes, int n_in,
                              void* d_out, int out_size, void* d_ws, size_t ws_size,
                              hipStream_t stream) {
    const float* lg = (const float*)d_in[0];
    const float* tg = (const float*)d_in[1];
    const int* epoch = (const int*)d_in[2];
    float* out = (float*)d_out;
    unsigned* ob = (unsigned*)d_out;
    unsigned* ws = (unsigned*)d_ws;
    long long n = (long long)in_sizes[0];

    hipMemsetAsync(d_ws, 0, (size_t)ZERO_WORDS * 4, stream);

    const int blocks = 2048, threads = 256;
    kA_store_hist<<<blocks, threads, 0, stream>>>(lg, tg, out, ws, n);
    k2_sel12<<<1, 256, 0, stream>>>(ws, epoch);
    kB_hist64<<<blocks, threads, 0, stream>>>(lg, ob, ws, n);
    k4_sel64<<<1, 64, 0, stream>>>(ws);
    kC_histwin<<<blocks, threads, 0, stream>>>(lg, ob, ws, n);
    k6_selwin<<<1, 1024, 0, stream>>>(ws);
    kD_final<<<blocks, threads, 0, stream>>>(lg, ob, ws, n);
}